// Round 14
// baseline (205.431 us; speedup 1.0000x reference)
//
#include <hip/hip_runtime.h>
#include <hip/hip_bf16.h>

#define BATCH 4096
#define HIDDEN 512
#define BN_EPS 1e-5f
#define STAGE_CAP 1024

typedef unsigned int u32;
typedef unsigned short u16;
typedef unsigned char u8;
typedef float f32x4 __attribute__((ext_vector_type(4)));
typedef __bf16 bf16x8 __attribute__((ext_vector_type(8)));

__device__ __forceinline__ float bf2f(u32 lo) { return __uint_as_float(lo << 16); }
__device__ __forceinline__ u32 f2bf(float f) {
    u32 u = __float_as_uint(f);
    return (u + 0x7FFFu + ((u >> 16) & 1u)) >> 16;          // round-to-nearest-even
}

// Inline dtype detection: per-wave ballot over 64 fixed probe words of emb.
__device__ __forceinline__ int detect_bf16(const u32* __restrict__ emb_w) {
    u32 v = emb_w[(size_t)(threadIdx.x & 63) * 400009u + 17u];
    float a = fabsf(bf2f(v & 0xffffu));
    bool bf_like = (a > 0.0009765625f) && (a < 16.0f);
    unsigned long long m = __ballot(bf_like);
    return __popcll(m) >= 48;
}

// ---------------------------------------------------------------------------
// K0b: blocks [0,nrb): emb -> INT8 table with per-row scale (rowmax/127).
//      blocks [nrb,nrb+64): LDS-tiled transpose W_h -> Wt bf16 [n][k].
//      block nrb+64: zero sums/sumsq/loss_acc/lcount/gdone.
__global__ __launch_bounds__(256) void k_convert(const void* __restrict__ emb,
                                                 u8* __restrict__ tab,
                                                 float* __restrict__ scales,
                                                 const void* __restrict__ W,
                                                 u16* __restrict__ Wt,
                                                 float* __restrict__ zero_base,
                                                 int vocab) {
    const int nrb = (vocab + 3) >> 2;
    if (blockIdx.x == (u32)(nrb + 64)) {
        for (int i = threadIdx.x; i < 2 * HIDDEN + 3; i += 256) zero_base[i] = 0.f;
        return;
    }
    const int bf = detect_bf16((const u32*)emb);
    if (blockIdx.x >= (u32)nrb) {
        __shared__ u16 tile[64][66];
        const int b2 = blockIdx.x - nrb;
        const int k0 = (b2 >> 3) * 64, n0 = (b2 & 7) * 64;
        const int c = threadIdx.x & 63, r4 = threadIdx.x >> 6;
#pragma unroll
        for (int i = 0; i < 16; ++i) {
            const int k = k0 + r4 + i * 4;
            u16 w;
            if (bf) w = ((const u16*)W)[(size_t)k * HIDDEN + n0 + c];
            else    w = (u16)f2bf(((const float*)W)[(size_t)k * HIDDEN + n0 + c]);
            tile[k - k0][c] = w;
        }
        __syncthreads();
#pragma unroll
        for (int i = 0; i < 16; ++i) {
            const int n = n0 + r4 + i * 4;
            Wt[(size_t)n * HIDDEN + k0 + c] = tile[c][n - n0];
        }
        return;
    }

    const int wv = threadIdx.x >> 6, lane = threadIdx.x & 63;
    const int row = blockIdx.x * 4 + wv;
    if (row >= vocab) return;

    float v[8];
    if (bf) {
        uint4 u = *(const uint4*)((const u16*)emb + (size_t)row * HIDDEN + lane * 8);
        v[0] = bf2f(u.x & 0xffffu); v[1] = bf2f(u.x >> 16);
        v[2] = bf2f(u.y & 0xffffu); v[3] = bf2f(u.y >> 16);
        v[4] = bf2f(u.z & 0xffffu); v[5] = bf2f(u.z >> 16);
        v[6] = bf2f(u.w & 0xffffu); v[7] = bf2f(u.w >> 16);
    } else {
        const f32x4* p = (const f32x4*)((const float*)emb + (size_t)row * HIDDEN + lane * 8);
        f32x4 a = __builtin_nontemporal_load(p);
        f32x4 b = __builtin_nontemporal_load(p + 1);
        v[0] = a.x; v[1] = a.y; v[2] = a.z; v[3] = a.w;
        v[4] = b.x; v[5] = b.y; v[6] = b.z; v[7] = b.w;
    }
    float m = 0.f;
#pragma unroll
    for (int k = 0; k < 8; ++k) m = fmaxf(m, fabsf(v[k]));
#pragma unroll
    for (int o = 32; o > 0; o >>= 1) m = fmaxf(m, __shfl_xor(m, o));
    const float s   = m * (1.0f / 127.0f);
    const float inv = (m > 0.f) ? (127.0f / m) : 0.f;
    int q[8];
#pragma unroll
    for (int k = 0; k < 8; ++k) q[k] = (int)rintf(v[k] * inv);
    uint2 o;
    o.x = (q[0] & 255) | ((q[1] & 255) << 8) | ((q[2] & 255) << 16) | ((u32)(q[3] & 255) << 24);
    o.y = (q[4] & 255) | ((q[5] & 255) << 8) | ((q[6] & 255) << 16) | ((u32)(q[7] & 255) << 24);
    *(uint2*)(tab + (size_t)row * HIDDEN + lane * 8) = o;
    if (lane == 0) scales[row] = s;
}

// ---------------------------------------------------------------------------
// K1: ragged mean-pool from the int8 table (uint2/token, unroll-4, LDS-staged
// token ids + scales). At the random-512B-granule delivered-BW floor.
__global__ __launch_bounds__(256) void k_pool(const int* __restrict__ tokens,
                                              const int* __restrict__ seg,
                                              const void* __restrict__ emb,
                                              const u8* __restrict__ tab,
                                              const float* __restrict__ scales,
                                              int use_table,
                                              u32* __restrict__ pooled_bf, int T) {
    const int bf = detect_bf16((const u32*)emb);
    const int b = blockIdx.x;
    int lo = 0, hi = T;
    while (lo < hi) { int m = (lo + hi) >> 1; if (seg[m] < b) lo = m + 1; else hi = m; }
    const int start = lo;
    hi = T;
    while (lo < hi) { int m = (lo + hi) >> 1; if (seg[m] < b + 1) lo = m + 1; else hi = m; }
    const int end = lo;
    const int cnt = end - start;

    const int wv = threadIdx.x >> 6;
    const int lane = threadIdx.x & 63;
    const int chunk = (cnt + 3) >> 2;
    const int ts = start + wv * chunk;
    const int te = min(ts + chunk, end);

    float acc[8] = {0.f,0.f,0.f,0.f,0.f,0.f,0.f,0.f};

    __shared__ int   stok[STAGE_CAP];
    __shared__ float ssc[STAGE_CAP];

#define DECQ(v_, s_) \
    acc[0] = fmaf(s_, (float)(int)(signed char)( v_.x        & 255u), acc[0]); \
    acc[1] = fmaf(s_, (float)(int)(signed char)((v_.x >>  8) & 255u), acc[1]); \
    acc[2] = fmaf(s_, (float)(int)(signed char)((v_.x >> 16) & 255u), acc[2]); \
    acc[3] = fmaf(s_, (float)(int)(signed char)( v_.x >> 24        ), acc[3]); \
    acc[4] = fmaf(s_, (float)(int)(signed char)( v_.y        & 255u), acc[4]); \
    acc[5] = fmaf(s_, (float)(int)(signed char)((v_.y >>  8) & 255u), acc[5]); \
    acc[6] = fmaf(s_, (float)(int)(signed char)((v_.y >> 16) & 255u), acc[6]); \
    acc[7] = fmaf(s_, (float)(int)(signed char)( v_.y >> 24        ), acc[7]);

    if (use_table && cnt <= STAGE_CAP) {
        for (int i = threadIdx.x; i < cnt; i += 256) {
            const int tk = tokens[start + i];
            stok[i] = tk;
            ssc[i]  = scales[tk];
        }
        __syncthreads();
        int t = ts;
        for (; t + 4 <= te; t += 4) {
            const int i = t - start;
            const int tk0 = stok[i],     tk1 = stok[i + 1];
            const int tk2 = stok[i + 2], tk3 = stok[i + 3];
            const float s0 = ssc[i],     s1 = ssc[i + 1];
            const float s2 = ssc[i + 2], s3 = ssc[i + 3];
            uint2 v0 = *(const uint2*)(tab + (size_t)tk0 * HIDDEN + lane * 8);
            uint2 v1 = *(const uint2*)(tab + (size_t)tk1 * HIDDEN + lane * 8);
            uint2 v2 = *(const uint2*)(tab + (size_t)tk2 * HIDDEN + lane * 8);
            uint2 v3 = *(const uint2*)(tab + (size_t)tk3 * HIDDEN + lane * 8);
            DECQ(v0, s0); DECQ(v1, s1); DECQ(v2, s2); DECQ(v3, s3);
        }
        for (; t < te; ++t) {
            const int i = t - start;
            const int tk = stok[i];
            const float s = ssc[i];
            uint2 v = *(const uint2*)(tab + (size_t)tk * HIDDEN + lane * 8);
            DECQ(v, s);
        }
    } else if (use_table) {
        int t = ts;
        for (; t + 4 <= te; t += 4) {
            const int tk0 = tokens[t],     tk1 = tokens[t + 1];
            const int tk2 = tokens[t + 2], tk3 = tokens[t + 3];
            const float s0 = scales[tk0], s1 = scales[tk1];
            const float s2 = scales[tk2], s3 = scales[tk3];
            uint2 v0 = *(const uint2*)(tab + (size_t)tk0 * HIDDEN + lane * 8);
            uint2 v1 = *(const uint2*)(tab + (size_t)tk1 * HIDDEN + lane * 8);
            uint2 v2 = *(const uint2*)(tab + (size_t)tk2 * HIDDEN + lane * 8);
            uint2 v3 = *(const uint2*)(tab + (size_t)tk3 * HIDDEN + lane * 8);
            DECQ(v0, s0); DECQ(v1, s1); DECQ(v2, s2); DECQ(v3, s3);
        }
        for (; t < te; ++t) {
            const int tk = tokens[t];
            const float s = scales[tk];
            uint2 v = *(const uint2*)(tab + (size_t)tk * HIDDEN + lane * 8);
            DECQ(v, s);
        }
    } else if (bf) {
        const u16* src = (const u16*)emb;
        for (int t = ts; t < te; ++t) {
            uint4 v = *(const uint4*)(src + (size_t)tokens[t] * HIDDEN + lane * 8);
            acc[0] += bf2f(v.x & 0xffffu); acc[1] += bf2f(v.x >> 16);
            acc[2] += bf2f(v.y & 0xffffu); acc[3] += bf2f(v.y >> 16);
            acc[4] += bf2f(v.z & 0xffffu); acc[5] += bf2f(v.z >> 16);
            acc[6] += bf2f(v.w & 0xffffu); acc[7] += bf2f(v.w >> 16);
        }
    } else {
        const float* e = (const float*)emb;
        for (int t = ts; t < te; ++t) {
            const float* p = e + (size_t)tokens[t] * HIDDEN + lane * 8;
            float4 a = *(const float4*)p, b2_ = *(const float4*)(p + 4);
            acc[0] += a.x; acc[1] += a.y; acc[2] += a.z; acc[3] += a.w;
            acc[4] += b2_.x; acc[5] += b2_.y; acc[6] += b2_.z; acc[7] += b2_.w;
        }
    }
#undef DECQ

    __shared__ float red[4][8][64];
    if (wv > 0) {
#pragma unroll
        for (int k = 0; k < 8; ++k) red[wv][k][lane] = acc[k];
    }
    __syncthreads();
    if (wv == 0) {
#pragma unroll
        for (int k = 0; k < 8; ++k)
            acc[k] += red[1][k][lane] + red[2][k][lane] + red[3][k][lane];
        const float inv = (cnt > 0) ? (1.0f / (float)cnt) : 1.0f;
        uint4 o;
        o.x = f2bf(acc[0] * inv) | (f2bf(acc[1] * inv) << 16);
        o.y = f2bf(acc[2] * inv) | (f2bf(acc[3] * inv) << 16);
        o.z = f2bf(acc[4] * inv) | (f2bf(acc[5] * inv) << 16);
        o.w = f2bf(acc[6] * inv) | (f2bf(acc[7] * inv) << 16);
        *(uint4*)(pooled_bf + (size_t)b * (HIDDEN / 2) + lane * 4) = o;
    }
}

// ---------------------------------------------------------------------------
// K2 (FUSED gemm+BNstats+BN+ReLU+Wo+loss): 256 blocks x 16 rows x 512 cols.
// h never hits memory: MFMA acc stays in registers across a completion-counter
// barrier (256 blocks = 1/CU, all resident -> deadlock-free), then BN+dot
// applied per-lane and reduced (shfl over l15 -> LDS over wave/hi).
__global__ __launch_bounds__(256) void k_gemm_out(const u32* __restrict__ pooled_bf,
                                                  const void* __restrict__ W,
                                                  const u16* __restrict__ Wt,
                                                  const void* __restrict__ bias,
                                                  const void* __restrict__ gamma,
                                                  const void* __restrict__ beta,
                                                  const void* __restrict__ W_o,
                                                  const void* __restrict__ b_o,
                                                  const void* __restrict__ tvec,
                                                  const u32* __restrict__ embw,
                                                  int use_wt,
                                                  float* __restrict__ sums,
                                                  float* __restrict__ sumsq,
                                                  float* __restrict__ loss_acc,
                                                  u32* __restrict__ lcount,
                                                  u32* __restrict__ gdone,
                                                  void* __restrict__ out) {
    __shared__ float ws_s[4][8][16], ws_q[4][8][16];
    __shared__ float rowpart[4][16];
    __shared__ float lterm[16];
    const int bf = detect_bf16(embw);
    const int tid  = threadIdx.x;
    const int wv   = tid >> 6;
    const int lane = tid & 63;
    const int l15  = lane & 15;
    const int hi   = lane >> 4;                 // 0..3
    const int rb   = blockIdx.x * 16;           // 16 rows per block
    const int mrow = rb + l15;
    const float invN = 1.0f / (float)BATCH;

    f32x4 acc[8] = {};

    // ---- GEMM: rows rb..rb+15, cols wv*128..+127, K=512 ----
    for (int k0 = 0; k0 < HIDDEN; k0 += 32) {
        const int kb = k0 + hi * 8;
        uint4 av = *(const uint4*)(pooled_bf + (size_t)mrow * (HIDDEN / 2) + (kb >> 1));
        bf16x8 afrag = __builtin_bit_cast(bf16x8, av);
#pragma unroll
        for (int j = 0; j < 8; ++j) {
            const int n = wv * 128 + j * 16 + l15;
            bf16x8 bfrag;
            if (use_wt) {
                uint4 bv = *(const uint4*)(Wt + (size_t)n * HIDDEN + kb);
                bfrag = __builtin_bit_cast(bf16x8, bv);
            } else {
                u16 bw[8];
                if (bf) {
                    const u16* Wb = (const u16*)W;
#pragma unroll
                    for (int i = 0; i < 8; ++i) bw[i] = Wb[(size_t)(kb + i) * HIDDEN + n];
                } else {
                    const float* Wf = (const float*)W;
#pragma unroll
                    for (int i = 0; i < 8; ++i) bw[i] = (u16)f2bf(Wf[(size_t)(kb + i) * HIDDEN + n]);
                }
                uint4 bv;
                bv.x = bw[0] | ((u32)bw[1] << 16);
                bv.y = bw[2] | ((u32)bw[3] << 16);
                bv.z = bw[4] | ((u32)bw[5] << 16);
                bv.w = bw[6] | ((u32)bw[7] << 16);
                bfrag = __builtin_bit_cast(bf16x8, bv);
            }
            acc[j] = __builtin_amdgcn_mfma_f32_16x16x32_bf16(afrag, bfrag, acc[j], 0, 0, 0);
        }
    }

    // bias add into acc, column stats -> global atomics
    float bv8[8];
#pragma unroll
    for (int j = 0; j < 8; ++j) {
        const int n = wv * 128 + j * 16 + l15;
        bv8[j] = bf ? bf2f(((const u16*)bias)[n]) : ((const float*)bias)[n];
        float s = 0.f, q = 0.f;
#pragma unroll
        for (int r = 0; r < 4; ++r) {
            acc[j][r] += bv8[j];
            s += acc[j][r];
            q = fmaf(acc[j][r], acc[j][r], q);
        }
        s += __shfl_xor(s, 16); s += __shfl_xor(s, 32);
        q += __shfl_xor(q, 16); q += __shfl_xor(q, 32);
        if (lane < 16) { ws_s[wv][j][l15] = s; ws_q[wv][j][l15] = q; }
    }
    __syncthreads();
    // 256 threads cover this block's 512 cols (2 cols each): wv*128+j*16+c
    {
        const int c2 = tid * 2;
        const int w2 = c2 >> 7, rem = c2 & 127, j2 = rem >> 4, cc = rem & 15;
        atomicAdd(&sums[c2],      ws_s[w2][j2][cc]);
        atomicAdd(&sumsq[c2],     ws_q[w2][j2][cc]);
        const int c3 = c2 + 1;
        const int w3 = c3 >> 7, rem3 = c3 & 127, j3 = rem3 >> 4, cc3 = rem3 & 15;
        atomicAdd(&sums[c3],      ws_s[w3][j3][cc3]);
        atomicAdd(&sumsq[c3],     ws_q[w3][j3][cc3]);
    }

    // ---- device-wide stats barrier (all 256 blocks resident) ----
    if (tid == 0) {
        __threadfence();
        atomicAdd(gdone, 1u);
        while (atomicAdd(gdone, 0u) < gridDim.x) __builtin_amdgcn_s_sleep(8);
    }
    __syncthreads();
    __threadfence();

    // ---- BN + ReLU + dot W_o per lane on its own acc values ----
    float part[4] = {0.f, 0.f, 0.f, 0.f};
#pragma unroll
    for (int j = 0; j < 8; ++j) {
        const int n = wv * 128 + j * 16 + l15;
        const float sm = __hip_atomic_load(&sums[n],  __ATOMIC_RELAXED, __HIP_MEMORY_SCOPE_AGENT);
        const float sq = __hip_atomic_load(&sumsq[n], __ATOMIC_RELAXED, __HIP_MEMORY_SCOPE_AGENT);
        const float mu  = sm * invN;
        const float var = sq * invN - mu * mu;
        const float rs  = rsqrtf(var + BN_EPS);
        const float gn  = bf ? bf2f(((const u16*)gamma)[n]) : ((const float*)gamma)[n];
        const float btn = bf ? bf2f(((const u16*)beta)[n])  : ((const float*)beta)[n];
        const float won = bf ? bf2f(((const u16*)W_o)[n])   : ((const float*)W_o)[n];
#pragma unroll
        for (int r = 0; r < 4; ++r) {
            float y = fmaf(gn, (acc[j][r] - mu) * rs, btn);
            y = fmaxf(y, 0.f);
            part[r] = fmaf(y, won, part[r]);
        }
    }
#pragma unroll
    for (int o = 8; o > 0; o >>= 1) {
#pragma unroll
        for (int r = 0; r < 4; ++r) part[r] += __shfl_xor(part[r], o);
    }
    if (l15 == 0) {
#pragma unroll
        for (int r = 0; r < 4; ++r) rowpart[wv][hi * 4 + r] = part[r];
    }
    __syncthreads();

    if (tid < 16) {
        const int row = rb + tid;
        float dot = rowpart[0][tid] + rowpart[1][tid] + rowpart[2][tid] + rowpart[3][tid];
        const float bo = bf ? bf2f(((const u16*)b_o)[0]) : ((const float*)b_o)[0];
        const float x = dot + bo;
        if (bf) ((u16*)out)[1 + row] = (u16)f2bf(x);
        else    ((float*)out)[1 + row] = x;
        const float t = bf ? bf2f(((const u16*)tvec)[row]) : ((const float*)tvec)[row];
        const float sp = fmaxf(x, 0.f) + log1pf(expf(-fabsf(x)));
        lterm[tid] = sp - t * x;
    }
    __syncthreads();
    if (tid == 0) {
        float bl = 0.f;
#pragma unroll
        for (int i = 0; i < 16; ++i) bl += lterm[i];
        atomicAdd(loss_acc, bl);
        __threadfence();
        u32 old = atomicAdd(lcount, 1u);
        if (old == gridDim.x - 1) {
            float v = atomicAdd(loss_acc, 0.0f) * (1.0f / (float)BATCH);
            if (bf) ((u16*)out)[0] = (u16)f2bf(v);
            else    ((float*)out)[0] = v;
        }
    }
}

// ---------------------------------------------------------------------------
extern "C" void kernel_launch(void* const* d_in, const int* in_sizes, int n_in,
                              void* d_out, int out_size, void* d_ws, size_t ws_size,
                              hipStream_t stream) {
    const int*  tokens = (const int*)d_in[0];
    const int*  seg    = (const int*)d_in[1];
    const void* tvec   = d_in[2];
    const void* emb    = d_in[3];
    const void* W_h    = d_in[4];
    const void* b_h    = d_in[5];
    const void* gamma  = d_in[6];
    const void* beta   = d_in[7];
    const void* W_o    = d_in[8];
    const void* b_o    = d_in[9];
    const int T = in_sizes[0];
    const int vocab = in_sizes[3] / HIDDEN;

    char* ws = (char*)d_ws;
    u32*   pooled_bf = (u32*)ws;                               // 4 MB (bf16-packed)
    float* sums      = (float*)(ws + (size_t)16 * 1024 * 1024);
    float* sumsq     = sums + HIDDEN;                          // [512]
    float* loss_acc  = sums + 2 * HIDDEN;                      // 1 f
    u32*   lcount    = (u32*)(loss_acc + 1);                   // 1 u32
    u32*   gdone     = (u32*)(loss_acc + 2);                   // 1 u32
    const size_t TABLE_OFF   = (size_t)17 * 1024 * 1024;
    const size_t TABLE_BYTES = (size_t)vocab * HIDDEN;         // int8: 51.2 MB
    const size_t SCALE_BYTES = (size_t)vocab * sizeof(float);  // 0.4 MB
    const size_t WT_BYTES    = (size_t)HIDDEN * HIDDEN * 2;    // 0.5 MB
    u8*    tab    = (u8*)(ws + TABLE_OFF);
    float* scales = (float*)(ws + TABLE_OFF + TABLE_BYTES);
    u16*   Wt     = (u16*)(ws + TABLE_OFF + TABLE_BYTES + SCALE_BYTES);
    const int use_table =
        (ws_size >= TABLE_OFF + TABLE_BYTES + SCALE_BYTES + WT_BYTES) ? 1 : 0;

    const int nrb = (vocab + 3) >> 2;
    if (use_table) {
        k_convert<<<nrb + 64 + 1, 256, 0, stream>>>(emb, tab, scales, W_h, Wt,
                                                    sums, vocab);
    } else {
        (void)hipMemsetAsync(sums, 0, (2 * HIDDEN + 3) * sizeof(float), stream);
    }
    k_pool<<<BATCH, 256, 0, stream>>>(tokens, seg, emb, tab, scales, use_table,
                                      pooled_bf, T);
    k_gemm_out<<<BATCH / 16, 256, 0, stream>>>(pooled_bf, W_h, Wt, b_h,
                                               gamma, beta, W_o, b_o, tvec,
                                               (const u32*)emb, use_table,
                                               sums, sumsq, loss_acc, lcount,
                                               gdone, d_out);
}

// Round 15
// 185.895 us; speedup vs baseline: 1.1051x; 1.1051x over previous
//
#include <hip/hip_runtime.h>
#include <hip/hip_bf16.h>

#define BATCH 4096
#define HIDDEN 512
#define BN_EPS 1e-5f
#define STAGE_CAP 512

typedef unsigned int u32;
typedef unsigned short u16;
typedef unsigned char u8;
typedef float f32x4 __attribute__((ext_vector_type(4)));
typedef __bf16 bf16x8 __attribute__((ext_vector_type(8)));

__device__ __forceinline__ float bf2f(u32 lo) { return __uint_as_float(lo << 16); }
__device__ __forceinline__ u32 f2bf(float f) {
    u32 u = __float_as_uint(f);
    return (u + 0x7FFFu + ((u >> 16) & 1u)) >> 16;          // round-to-nearest-even
}

// Inline dtype detection: per-wave ballot over 64 fixed probe words of emb.
__device__ __forceinline__ int detect_bf16(const u32* __restrict__ emb_w) {
    u32 v = emb_w[(size_t)(threadIdx.x & 63) * 400009u + 17u];
    float a = fabsf(bf2f(v & 0xffffu));
    bool bf_like = (a > 0.0009765625f) && (a < 16.0f);
    unsigned long long m = __ballot(bf_like);
    return __popcll(m) >= 48;
}

// ---------------------------------------------------------------------------
// K0b: blocks [0,nrb): emb -> INT8 table with per-row scale (rowmax/127).
//      blocks [nrb,nrb+64): LDS-tiled transpose W_h -> Wt bf16 [n][k].
//      block nrb+64: zero sums/sumsq/loss_acc/counter.
__global__ __launch_bounds__(256) void k_convert(const void* __restrict__ emb,
                                                 u8* __restrict__ tab,
                                                 float* __restrict__ scales,
                                                 const void* __restrict__ W,
                                                 u16* __restrict__ Wt,
                                                 float* __restrict__ zero_base,
                                                 int vocab) {
    const int nrb = (vocab + 3) >> 2;
    if (blockIdx.x == (u32)(nrb + 64)) {
        for (int i = threadIdx.x; i < 2 * HIDDEN + 2; i += 256) zero_base[i] = 0.f;
        return;
    }
    const int bf = detect_bf16((const u32*)emb);
    if (blockIdx.x >= (u32)nrb) {
        __shared__ u16 tile[64][66];
        const int b2 = blockIdx.x - nrb;
        const int k0 = (b2 >> 3) * 64, n0 = (b2 & 7) * 64;
        const int c = threadIdx.x & 63, r4 = threadIdx.x >> 6;
#pragma unroll
        for (int i = 0; i < 16; ++i) {
            const int k = k0 + r4 + i * 4;
            u16 w;
            if (bf) w = ((const u16*)W)[(size_t)k * HIDDEN + n0 + c];
            else    w = (u16)f2bf(((const float*)W)[(size_t)k * HIDDEN + n0 + c]);
            tile[k - k0][c] = w;
        }
        __syncthreads();
#pragma unroll
        for (int i = 0; i < 16; ++i) {
            const int n = n0 + r4 + i * 4;
            Wt[(size_t)n * HIDDEN + k0 + c] = tile[c][n - n0];
        }
        return;
    }

    const int wv = threadIdx.x >> 6, lane = threadIdx.x & 63;
    const int row = blockIdx.x * 4 + wv;
    if (row >= vocab) return;

    float v[8];
    if (bf) {
        uint4 u = *(const uint4*)((const u16*)emb + (size_t)row * HIDDEN + lane * 8);
        v[0] = bf2f(u.x & 0xffffu); v[1] = bf2f(u.x >> 16);
        v[2] = bf2f(u.y & 0xffffu); v[3] = bf2f(u.y >> 16);
        v[4] = bf2f(u.z & 0xffffu); v[5] = bf2f(u.z >> 16);
        v[6] = bf2f(u.w & 0xffffu); v[7] = bf2f(u.w >> 16);
    } else {
        const f32x4* p = (const f32x4*)((const float*)emb + (size_t)row * HIDDEN + lane * 8);
        f32x4 a = __builtin_nontemporal_load(p);
        f32x4 b = __builtin_nontemporal_load(p + 1);
        v[0] = a.x; v[1] = a.y; v[2] = a.z; v[3] = a.w;
        v[4] = b.x; v[5] = b.y; v[6] = b.z; v[7] = b.w;
    }
    float m = 0.f;
#pragma unroll
    for (int k = 0; k < 8; ++k) m = fmaxf(m, fabsf(v[k]));
#pragma unroll
    for (int o = 32; o > 0; o >>= 1) m = fmaxf(m, __shfl_xor(m, o));
    const float s   = m * (1.0f / 127.0f);
    const float inv = (m > 0.f) ? (127.0f / m) : 0.f;
    int q[8];
#pragma unroll
    for (int k = 0; k < 8; ++k) q[k] = (int)rintf(v[k] * inv);
    uint2 o;
    o.x = (q[0] & 255) | ((q[1] & 255) << 8) | ((q[2] & 255) << 16) | ((u32)(q[3] & 255) << 24);
    o.y = (q[4] & 255) | ((q[5] & 255) << 8) | ((q[6] & 255) << 16) | ((u32)(q[7] & 255) << 24);
    *(uint2*)(tab + (size_t)row * HIDDEN + lane * 8) = o;
    if (lane == 0) scales[row] = s;
}

// ---------------------------------------------------------------------------
// K1: ragged mean-pool from the int8 table (uint2/token, unroll-4, LDS-staged
// token ids + scales). At the random-512B-granule delivered-BW floor.
__global__ __launch_bounds__(256) void k_pool(const int* __restrict__ tokens,
                                              const int* __restrict__ seg,
                                              const void* __restrict__ emb,
                                              const u8* __restrict__ tab,
                                              const float* __restrict__ scales,
                                              int use_table,
                                              u32* __restrict__ pooled_bf, int T) {
    const int bf = detect_bf16((const u32*)emb);
    const int b = blockIdx.x;
    int lo = 0, hi = T;
    while (lo < hi) { int m = (lo + hi) >> 1; if (seg[m] < b) lo = m + 1; else hi = m; }
    const int start = lo;
    hi = T;
    while (lo < hi) { int m = (lo + hi) >> 1; if (seg[m] < b + 1) lo = m + 1; else hi = m; }
    const int end = lo;
    const int cnt = end - start;

    const int wv = threadIdx.x >> 6;
    const int lane = threadIdx.x & 63;
    const int chunk = (cnt + 3) >> 2;
    const int ts = start + wv * chunk;
    const int te = min(ts + chunk, end);

    float acc[8] = {0.f,0.f,0.f,0.f,0.f,0.f,0.f,0.f};

    __shared__ int   stok[STAGE_CAP];
    __shared__ float ssc[STAGE_CAP];

#define DECQ(v_, s_) \
    acc[0] = fmaf(s_, (float)(int)(signed char)( v_.x        & 255u), acc[0]); \
    acc[1] = fmaf(s_, (float)(int)(signed char)((v_.x >>  8) & 255u), acc[1]); \
    acc[2] = fmaf(s_, (float)(int)(signed char)((v_.x >> 16) & 255u), acc[2]); \
    acc[3] = fmaf(s_, (float)(int)(signed char)( v_.x >> 24        ), acc[3]); \
    acc[4] = fmaf(s_, (float)(int)(signed char)( v_.y        & 255u), acc[4]); \
    acc[5] = fmaf(s_, (float)(int)(signed char)((v_.y >>  8) & 255u), acc[5]); \
    acc[6] = fmaf(s_, (float)(int)(signed char)((v_.y >> 16) & 255u), acc[6]); \
    acc[7] = fmaf(s_, (float)(int)(signed char)( v_.y >> 24        ), acc[7]);

    if (use_table && cnt <= STAGE_CAP) {
        for (int i = threadIdx.x; i < cnt; i += 256) {
            const int tk = tokens[start + i];
            stok[i] = tk;
            ssc[i]  = scales[tk];
        }
        __syncthreads();
        int t = ts;
        for (; t + 4 <= te; t += 4) {
            const int i = t - start;
            const int tk0 = stok[i],     tk1 = stok[i + 1];
            const int tk2 = stok[i + 2], tk3 = stok[i + 3];
            const float s0 = ssc[i],     s1 = ssc[i + 1];
            const float s2 = ssc[i + 2], s3 = ssc[i + 3];
            uint2 v0 = *(const uint2*)(tab + (size_t)tk0 * HIDDEN + lane * 8);
            uint2 v1 = *(const uint2*)(tab + (size_t)tk1 * HIDDEN + lane * 8);
            uint2 v2 = *(const uint2*)(tab + (size_t)tk2 * HIDDEN + lane * 8);
            uint2 v3 = *(const uint2*)(tab + (size_t)tk3 * HIDDEN + lane * 8);
            DECQ(v0, s0); DECQ(v1, s1); DECQ(v2, s2); DECQ(v3, s3);
        }
        for (; t < te; ++t) {
            const int i = t - start;
            const int tk = stok[i];
            const float s = ssc[i];
            uint2 v = *(const uint2*)(tab + (size_t)tk * HIDDEN + lane * 8);
            DECQ(v, s);
        }
    } else if (use_table) {
        int t = ts;
        for (; t + 4 <= te; t += 4) {
            const int tk0 = tokens[t],     tk1 = tokens[t + 1];
            const int tk2 = tokens[t + 2], tk3 = tokens[t + 3];
            const float s0 = scales[tk0], s1 = scales[tk1];
            const float s2 = scales[tk2], s3 = scales[tk3];
            uint2 v0 = *(const uint2*)(tab + (size_t)tk0 * HIDDEN + lane * 8);
            uint2 v1 = *(const uint2*)(tab + (size_t)tk1 * HIDDEN + lane * 8);
            uint2 v2 = *(const uint2*)(tab + (size_t)tk2 * HIDDEN + lane * 8);
            uint2 v3 = *(const uint2*)(tab + (size_t)tk3 * HIDDEN + lane * 8);
            DECQ(v0, s0); DECQ(v1, s1); DECQ(v2, s2); DECQ(v3, s3);
        }
        for (; t < te; ++t) {
            const int tk = tokens[t];
            const float s = scales[tk];
            uint2 v = *(const uint2*)(tab + (size_t)tk * HIDDEN + lane * 8);
            DECQ(v, s);
        }
    } else if (bf) {
        const u16* src = (const u16*)emb;
        for (int t = ts; t < te; ++t) {
            uint4 v = *(const uint4*)(src + (size_t)tokens[t] * HIDDEN + lane * 8);
            acc[0] += bf2f(v.x & 0xffffu); acc[1] += bf2f(v.x >> 16);
            acc[2] += bf2f(v.y & 0xffffu); acc[3] += bf2f(v.y >> 16);
            acc[4] += bf2f(v.z & 0xffffu); acc[5] += bf2f(v.z >> 16);
            acc[6] += bf2f(v.w & 0xffffu); acc[7] += bf2f(v.w >> 16);
        }
    } else {
        const float* e = (const float*)emb;
        for (int t = ts; t < te; ++t) {
            const float* p = e + (size_t)tokens[t] * HIDDEN + lane * 8;
            float4 a = *(const float4*)p, b2_ = *(const float4*)(p + 4);
            acc[0] += a.x; acc[1] += a.y; acc[2] += a.z; acc[3] += a.w;
            acc[4] += b2_.x; acc[5] += b2_.y; acc[6] += b2_.z; acc[7] += b2_.w;
        }
    }
#undef DECQ

    __shared__ float red[4][8][64];
    if (wv > 0) {
#pragma unroll
        for (int k = 0; k < 8; ++k) red[wv][k][lane] = acc[k];
    }
    __syncthreads();
    if (wv == 0) {
#pragma unroll
        for (int k = 0; k < 8; ++k)
            acc[k] += red[1][k][lane] + red[2][k][lane] + red[3][k][lane];
        const float inv = (cnt > 0) ? (1.0f / (float)cnt) : 1.0f;
        uint4 o;
        o.x = f2bf(acc[0] * inv) | (f2bf(acc[1] * inv) << 16);
        o.y = f2bf(acc[2] * inv) | (f2bf(acc[3] * inv) << 16);
        o.z = f2bf(acc[4] * inv) | (f2bf(acc[5] * inv) << 16);
        o.w = f2bf(acc[6] * inv) | (f2bf(acc[7] * inv) << 16);
        *(uint4*)(pooled_bf + (size_t)b * (HIDDEN / 2) + lane * 4) = o;
    }
}

// ---------------------------------------------------------------------------
// K2: h = pooled @ W_h + b_h via MFMA 16x16x32 bf16, fused BN column stats
// (shuffle-reduce -> per-wave LDS slot -> 64 global atomics). h stored BF16
// (stats from f32 accumulators, so only the k_out readback quantizes).
__global__ __launch_bounds__(256) void k_gemm(const u32* __restrict__ pooled_bf,
                                              const void* __restrict__ W,
                                              const u16* __restrict__ Wt,
                                              const void* __restrict__ bias,
                                              const u32* __restrict__ embw,
                                              int use_wt,
                                              u16* __restrict__ hbf,
                                              float* __restrict__ sums,
                                              float* __restrict__ sumsq) {
    __shared__ float ws_s[4][4][16], ws_q[4][4][16];
    const int bf = detect_bf16(embw);
    const int tid  = threadIdx.x;
    const int wv   = tid >> 6;
    const int lane = tid & 63;
    const int l15  = lane & 15;
    const int hi   = lane >> 4;
    const int rb   = (blockIdx.x >> 3) * 64;
    const int nb   = (blockIdx.x & 7) * 64;
    const int mrow = rb + wv * 16 + l15;

    f32x4 acc[4] = {};

    for (int k0 = 0; k0 < HIDDEN; k0 += 32) {
        const int kb = k0 + hi * 8;
        uint4 av = *(const uint4*)(pooled_bf + (size_t)mrow * (HIDDEN / 2) + (kb >> 1));
        bf16x8 afrag = __builtin_bit_cast(bf16x8, av);
#pragma unroll
        for (int j = 0; j < 4; ++j) {
            const int n = nb + j * 16 + l15;
            bf16x8 bfrag;
            if (use_wt) {
                uint4 bv = *(const uint4*)(Wt + (size_t)n * HIDDEN + kb);
                bfrag = __builtin_bit_cast(bf16x8, bv);
            } else {
                u16 bw[8];
                if (bf) {
                    const u16* Wb = (const u16*)W;
#pragma unroll
                    for (int i = 0; i < 8; ++i) bw[i] = Wb[(size_t)(kb + i) * HIDDEN + n];
                } else {
                    const float* Wf = (const float*)W;
#pragma unroll
                    for (int i = 0; i < 8; ++i) bw[i] = (u16)f2bf(Wf[(size_t)(kb + i) * HIDDEN + n]);
                }
                uint4 bv;
                bv.x = bw[0] | ((u32)bw[1] << 16);
                bv.y = bw[2] | ((u32)bw[3] << 16);
                bv.z = bw[4] | ((u32)bw[5] << 16);
                bv.w = bw[6] | ((u32)bw[7] << 16);
                bfrag = __builtin_bit_cast(bf16x8, bv);
            }
            acc[j] = __builtin_amdgcn_mfma_f32_16x16x32_bf16(afrag, bfrag, acc[j], 0, 0, 0);
        }
    }

#pragma unroll
    for (int j = 0; j < 4; ++j) {
        const int n = nb + j * 16 + l15;
        const float bvn = bf ? bf2f(((const u16*)bias)[n]) : ((const float*)bias)[n];
        float s = 0.f, q = 0.f;
#pragma unroll
        for (int r = 0; r < 4; ++r) {
            const int row = rb + wv * 16 + hi * 4 + r;
            const float v = acc[j][r] + bvn;
            hbf[(size_t)row * HIDDEN + n] = (u16)f2bf(v);
            s += v;
            q = fmaf(v, v, q);
        }
        s += __shfl_xor(s, 16); s += __shfl_xor(s, 32);
        q += __shfl_xor(q, 16); q += __shfl_xor(q, 32);
        if (lane < 16) { ws_s[wv][j][l15] = s; ws_q[wv][j][l15] = q; }
    }
    __syncthreads();
    if (tid < 64) {
        const int j2 = tid >> 4, c = tid & 15;
        float ts = ws_s[0][j2][c] + ws_s[1][j2][c] + ws_s[2][j2][c] + ws_s[3][j2][c];
        float tq = ws_q[0][j2][c] + ws_q[1][j2][c] + ws_q[2][j2][c] + ws_q[3][j2][c];
        atomicAdd(&sums[nb + j2 * 16 + c],  ts);
        atomicAdd(&sumsq[nb + j2 * 16 + c], tq);
    }
}

// ---------------------------------------------------------------------------
// K4: BN(batch stats) + ReLU + dot W_o + b_o -> logits; per-row BCE term.
// Completion counter: last of the 1024 blocks finalizes the mean loss.
// h read as bf16 (uint4 = 8 channels per lane).
__global__ __launch_bounds__(256) void k_out(const u16* __restrict__ hbf,
                                             const float* __restrict__ sums,
                                             const float* __restrict__ sumsq,
                                             const void* __restrict__ gamma,
                                             const void* __restrict__ beta,
                                             const void* __restrict__ W_o,
                                             const void* __restrict__ b_o,
                                             const void* __restrict__ tvec,
                                             const u32* __restrict__ embw,
                                             void* __restrict__ out,
                                             float* __restrict__ loss_acc,
                                             u32* __restrict__ counter) {
    const int bf = detect_bf16(embw);
    const int lane = threadIdx.x & 63;
    const int wave = threadIdx.x >> 6;
    const int row  = blockIdx.x * 4 + wave;
    const float invN = 1.0f / (float)BATCH;
    const int c0 = lane * 8;

    float g[8], bt[8], wo[8];
    if (bf) {
        uint4 gu = *(const uint4*)((const u32*)gamma + lane * 4);
        uint4 bu = *(const uint4*)((const u32*)beta  + lane * 4);
        uint4 wu = *(const uint4*)((const u32*)W_o   + lane * 4);
        g[0]=bf2f(gu.x&0xffffu); g[1]=bf2f(gu.x>>16); g[2]=bf2f(gu.y&0xffffu); g[3]=bf2f(gu.y>>16);
        g[4]=bf2f(gu.z&0xffffu); g[5]=bf2f(gu.z>>16); g[6]=bf2f(gu.w&0xffffu); g[7]=bf2f(gu.w>>16);
        bt[0]=bf2f(bu.x&0xffffu); bt[1]=bf2f(bu.x>>16); bt[2]=bf2f(bu.y&0xffffu); bt[3]=bf2f(bu.y>>16);
        bt[4]=bf2f(bu.z&0xffffu); bt[5]=bf2f(bu.z>>16); bt[6]=bf2f(bu.w&0xffffu); bt[7]=bf2f(bu.w>>16);
        wo[0]=bf2f(wu.x&0xffffu); wo[1]=bf2f(wu.x>>16); wo[2]=bf2f(wu.y&0xffffu); wo[3]=bf2f(wu.y>>16);
        wo[4]=bf2f(wu.z&0xffffu); wo[5]=bf2f(wu.z>>16); wo[6]=bf2f(wu.w&0xffffu); wo[7]=bf2f(wu.w>>16);
    } else {
        float4 a, b2;
        a = *(const float4*)((const float*)gamma + c0); b2 = *(const float4*)((const float*)gamma + c0 + 4);
        g[0]=a.x; g[1]=a.y; g[2]=a.z; g[3]=a.w; g[4]=b2.x; g[5]=b2.y; g[6]=b2.z; g[7]=b2.w;
        a = *(const float4*)((const float*)beta + c0);  b2 = *(const float4*)((const float*)beta + c0 + 4);
        bt[0]=a.x; bt[1]=a.y; bt[2]=a.z; bt[3]=a.w; bt[4]=b2.x; bt[5]=b2.y; bt[6]=b2.z; bt[7]=b2.w;
        a = *(const float4*)((const float*)W_o + c0);   b2 = *(const float4*)((const float*)W_o + c0 + 4);
        wo[0]=a.x; wo[1]=a.y; wo[2]=a.z; wo[3]=a.w; wo[4]=b2.x; wo[5]=b2.y; wo[6]=b2.z; wo[7]=b2.w;
    }

    float hv[8], sm[8], sq[8];
    {
        uint4 hu = *(const uint4*)(hbf + (size_t)row * HIDDEN + c0);
        hv[0]=bf2f(hu.x&0xffffu); hv[1]=bf2f(hu.x>>16); hv[2]=bf2f(hu.y&0xffffu); hv[3]=bf2f(hu.y>>16);
        hv[4]=bf2f(hu.z&0xffffu); hv[5]=bf2f(hu.z>>16); hv[6]=bf2f(hu.w&0xffffu); hv[7]=bf2f(hu.w>>16);
        float4 a = *(const float4*)(sums + c0), b2 = *(const float4*)(sums + c0 + 4);
        sm[0]=a.x; sm[1]=a.y; sm[2]=a.z; sm[3]=a.w; sm[4]=b2.x; sm[5]=b2.y; sm[6]=b2.z; sm[7]=b2.w;
        a = *(const float4*)(sumsq + c0); b2 = *(const float4*)(sumsq + c0 + 4);
        sq[0]=a.x; sq[1]=a.y; sq[2]=a.z; sq[3]=a.w; sq[4]=b2.x; sq[5]=b2.y; sq[6]=b2.z; sq[7]=b2.w;
    }

    float sum = 0.f;
#pragma unroll
    for (int k = 0; k < 8; ++k) {
        float mu  = sm[k] * invN;
        float var = sq[k] * invN - mu * mu;
        float xn  = (hv[k] - mu) * rsqrtf(var + BN_EPS);
        float y   = fmaf(g[k], xn, bt[k]);
        y = fmaxf(y, 0.f);
        sum = fmaf(y, wo[k], sum);
    }
#pragma unroll
    for (int o = 32; o > 0; o >>= 1) sum += __shfl_xor(sum, o);

    __shared__ float ls[4];
    if (lane == 0) {
        float bo = bf ? bf2f(((const u16*)b_o)[0]) : ((const float*)b_o)[0];
        float x = sum + bo;
        if (bf) ((u16*)out)[1 + row] = (u16)f2bf(x);
        else    ((float*)out)[1 + row] = x;
        float t = bf ? bf2f(((const u16*)tvec)[row]) : ((const float*)tvec)[row];
        float sp = fmaxf(x, 0.f) + log1pf(expf(-fabsf(x)));
        ls[wave] = sp - t * x;
    }
    __syncthreads();
    if (threadIdx.x == 0) {
        atomicAdd(loss_acc, ls[0] + ls[1] + ls[2] + ls[3]);
        __threadfence();
        u32 old = atomicAdd(counter, 1u);
        if (old == gridDim.x - 1) {
            float v = atomicAdd(loss_acc, 0.0f) * (1.0f / (float)BATCH);
            if (bf) ((u16*)out)[0] = (u16)f2bf(v);
            else    ((float*)out)[0] = v;
        }
    }
}

// ---------------------------------------------------------------------------
extern "C" void kernel_launch(void* const* d_in, const int* in_sizes, int n_in,
                              void* d_out, int out_size, void* d_ws, size_t ws_size,
                              hipStream_t stream) {
    const int*  tokens = (const int*)d_in[0];
    const int*  seg    = (const int*)d_in[1];
    const void* tvec   = d_in[2];
    const void* emb    = d_in[3];
    const void* W_h    = d_in[4];
    const void* b_h    = d_in[5];
    const void* gamma  = d_in[6];
    const void* beta   = d_in[7];
    const void* W_o    = d_in[8];
    const void* b_o    = d_in[9];
    const int T = in_sizes[0];
    const int vocab = in_sizes[3] / HIDDEN;

    char* ws = (char*)d_ws;
    u32*   pooled_bf = (u32*)ws;                               // 4 MB (bf16-packed)
    u16*   hbf       = (u16*)(ws + (size_t)8 * 1024 * 1024);   // 4 MB (bf16)
    float* sums      = (float*)(ws + (size_t)16 * 1024 * 1024);
    float* sumsq     = sums + HIDDEN;                          // [512]
    float* loss_acc  = sums + 2 * HIDDEN;                      // 1 f
    u32*   counter   = (u32*)(loss_acc + 1);                   // 1 u32
    const size_t TABLE_OFF   = (size_t)17 * 1024 * 1024;
    const size_t TABLE_BYTES = (size_t)vocab * HIDDEN;         // int8: 51.2 MB
    const size_t SCALE_BYTES = (size_t)vocab * sizeof(float);  // 0.4 MB
    const size_t WT_BYTES    = (size_t)HIDDEN * HIDDEN * 2;    // 0.5 MB
    u8*    tab    = (u8*)(ws + TABLE_OFF);
    float* scales = (float*)(ws + TABLE_OFF + TABLE_BYTES);
    u16*   Wt     = (u16*)(ws + TABLE_OFF + TABLE_BYTES + SCALE_BYTES);
    const int use_table =
        (ws_size >= TABLE_OFF + TABLE_BYTES + SCALE_BYTES + WT_BYTES) ? 1 : 0;

    const int nrb = (vocab + 3) >> 2;
    if (use_table) {
        k_convert<<<nrb + 64 + 1, 256, 0, stream>>>(emb, tab, scales, W_h, Wt,
                                                    sums, vocab);
    } else {
        (void)hipMemsetAsync(sums, 0, (2 * HIDDEN + 2) * sizeof(float), stream);
    }
    k_pool<<<BATCH, 256, 0, stream>>>(tokens, seg, emb, tab, scales, use_table,
                                      pooled_bf, T);
    k_gemm<<<(BATCH / 64) * 8, 256, 0, stream>>>(pooled_bf, W_h, Wt, b_h,
                                                 (const u32*)emb, use_table,
                                                 hbf, sums, sumsq);
    k_out<<<BATCH / 4, 256, 0, stream>>>(hbf, sums, sumsq, gamma, beta,
                                         W_o, b_o, tvec, (const u32*)emb, d_out,
                                         loss_acc, counter);
}